// Round 5
// baseline (852.115 us; speedup 1.0000x reference)
//
#include <hip/hip_runtime.h>
#include <math.h>

#define C_CH 54
#define CP   64      // candidate row stride: [0..53]=cand, 54=candsq, 55=tcand, 56=libmean
#define NT   20
#define NM   6
#define NK   120     // NM * NT
#define BLK  256

typedef float sf16 __attribute__((ext_vector_type(16)));
typedef float sf8  __attribute__((ext_vector_type(8)));

// ---------------- prep: candidate table (CP=64 rows) into workspace ----------------
__global__ __launch_bounds__(256) void hadar_prep(
    const float* __restrict__ s_sky, const float* __restrict__ s_ground,
    const float* __restrict__ library, const float* __restrict__ wg,
    float* __restrict__ cand)
{
    __shared__ float xamb[C_CH];
    __shared__ float tc[NT];
    __shared__ float lm[NM];
    const int tid = threadIdx.x;
    if (tid < NT) tc[tid] = 250.0f + (float)tid * (100.0f / 19.0f);
    if (tid < C_CH) xamb[tid] = 0.5f * s_sky[tid] + 0.5f * s_ground[tid];
    if (tid < NM) {
        float s = 0.0f;
        for (int c = 0; c < C_CH; ++c) s += library[tid * C_CH + c];
        lm[tid] = s / (float)C_CH;
    }
    __syncthreads();

    const float c1 = 1.191042e-8f, c2 = 1.4387752f;
    for (int idx = tid; idx < NK * CP; idx += 256) {
        const int k = idx >> 6, c = idx & 63;
        float v = 0.0f;
        if (c < C_CH) {
            const int m = k / NT, t = k - m * NT;
            const float nu = wg[c];
            const float B = c1 * nu * nu * nu / expm1f(c2 * nu / tc[t]);
            const float e = library[m * C_CH + c];
            v = e * B + (1.0f - e) * xamb[c];
        }
        cand[idx] = v;
    }
    __syncthreads();

    if (tid < NK) {
        float s = 0.0f;
        for (int c = 0; c < C_CH; ++c) { float v = cand[tid * CP + c]; s += v * v; }
        const int m = tid / NT, t = tid - m * NT;
        cand[tid * CP + 54] = s;        // candsq
        cand[tid * CP + 55] = tc[t];    // best_t value for this k
        cand[tid * CP + 56] = lm[m];    // texture value for this k
    }
}

// element c of the current candidate row held in SGPRs (c is compile-time after unroll)
#define CE(c) ((c) < 16 ? q0[(c)] : (c) < 32 ? q1[(c)-16] : (c) < 48 ? q2[(c)-32] : q3[(c)-48])

// ---------------- main: one pixel per thread, candidate rows via scalar loads ----------
// PIX=1: ~70 live VGPRs (54 row + accums + misc) fits the allocator's natural
// budget -> no scratch spills (round-4's PIX=2 needed 108 and spilled ~100 MB).
__global__ __launch_bounds__(BLK) void hadar_main(
    const float* __restrict__ s_obs,
    const float* __restrict__ library,
    const float* __restrict__ cand,
    float* __restrict__ out, float* __restrict__ partials, int N)
{
    const int tid = threadIdx.x;
    const long long n0 = (long long)blockIdx.x * BLK + tid;
    const bool v0 = (n0 < N);

    // pixel row in VGPRs (54 floats)
    float row0[C_CH];
    if (v0) {
        const float2* rp = (const float2*)(s_obs + n0 * C_CH);
        #pragma unroll
        for (int i = 0; i < C_CH / 2; ++i) {
            float2 w = rp[i];
            row0[2 * i] = w.x; row0[2 * i + 1] = w.y;
        }
    } else {
        #pragma unroll
        for (int c = 0; c < C_CH; ++c) row0[c] = 0.0f;
    }

    // ssq, same sequential order as round 1
    float ssq0 = 0.0f;
    #pragma unroll
    for (int c = 0; c < C_CH; ++c) ssq0 += row0[c] * row0[c];

    float bl0 = 3.4e38f;
    int bk0 = 0;

    const float* pk = cand;
    #pragma unroll 1
    for (int k = 0; k < NK; ++k, pk += CP) {
        sf16 q0, q1, q2;
        sf8  q3;
        asm volatile("s_load_dwordx16 %0, %1, 0x0"  : "=s"(q0) : "s"(pk));
        asm volatile("s_load_dwordx16 %0, %1, 0x40" : "=s"(q1) : "s"(pk));
        asm volatile("s_load_dwordx16 %0, %1, 0x80" : "=s"(q2) : "s"(pk));
        asm volatile("s_load_dwordx8  %0, %1, 0xc0" : "=s"(q3) : "s"(pk));
        // tie the wait to the loaded values so consumers can't be hoisted above it
        asm volatile("s_waitcnt lgkmcnt(0)" : "+s"(q0), "+s"(q1), "+s"(q2), "+s"(q3));

        float a0[4] = {0.f, 0.f, 0.f, 0.f};
        #pragma unroll
        for (int c = 0; c < C_CH; ++c) {
            a0[c & 3] += row0[c] * CE(c);
        }
        const float sq = q3[6];   // slot 54 = candsq
        const float d0 = (a0[0] + a0[1]) + (a0[2] + a0[3]);
        const float l0 = (ssq0 - 2.0f * d0) + sq;
        if (l0 < bl0) { bl0 = l0; bk0 = k; }
    }

    // ---- outputs ----
    const size_t NN = (size_t)N;
    const size_t NC = (size_t)C_CH * NN;
    float lsum = 0.0f;

    if (v0) {
        lsum = bl0;
        const int m = bk0 / NT;
        const float* crow = cand + (size_t)bk0 * CP;

        out[n0] = crow[55];                      // best_t
        out[NN + NC + n0] = 0.5f;                // best_v
        out[2 * NN + NC + n0] = 0.0f;            // beta
        out[3 * NN + NC + n0] = crow[56];        // texture

        // best_e = library[m]
        float2* bep = (float2*)(out + NN + (size_t)n0 * C_CH);
        const float2* lp = (const float2*)(library + m * C_CH);
        #pragma unroll
        for (int i = 0; i < C_CH / 2; ++i) bep[i] = lp[i];

        // s_recon = cand[bk0]
        float2* srp = (float2*)(out + 4 * NN + NC + (size_t)n0 * C_CH);
        const float2* cp2 = (const float2*)crow;
        #pragma unroll
        for (int i = 0; i < C_CH / 2; ++i) srp[i] = cp2[i];
    }

    // ---- deterministic block reduction of best_loss sum ----
    __shared__ float red[BLK];
    red[tid] = lsum;
    __syncthreads();
    #pragma unroll
    for (int s = BLK / 2; s > 0; s >>= 1) {
        if (tid < s) red[tid] += red[tid + s];
        __syncthreads();
    }
    if (tid == 0) partials[blockIdx.x] = red[0];
}

// ---------------- final reduce: objective = mean(best_loss) ----------------
__global__ __launch_bounds__(256) void hadar_reduce(
    const float* __restrict__ partials, int nb, float* __restrict__ obj_out, float invN)
{
    __shared__ float red[256];
    float s = 0.0f;
    for (int i = threadIdx.x; i < nb; i += 256) s += partials[i];
    red[threadIdx.x] = s;
    __syncthreads();
    #pragma unroll
    for (int st = 128; st > 0; st >>= 1) {
        if (threadIdx.x < st) red[threadIdx.x] += red[threadIdx.x + st];
        __syncthreads();
    }
    if (threadIdx.x == 0) *obj_out = red[0] * invN;
}

extern "C" void kernel_launch(void* const* d_in, const int* in_sizes, int n_in,
                              void* d_out, int out_size, void* d_ws, size_t ws_size,
                              hipStream_t stream)
{
    const float* s_obs    = (const float*)d_in[0];
    const float* s_sky    = (const float*)d_in[1];
    const float* s_ground = (const float*)d_in[2];
    const float* library  = (const float*)d_in[3];
    const float* wg       = (const float*)d_in[4];
    float* out = (float*)d_out;

    const int N  = in_sizes[0] / C_CH;
    const int nb = (N + BLK - 1) / BLK;

    float* ws       = (float*)d_ws;
    float* cand     = ws;              // NK*CP = 7680 floats
    float* partials = ws + 8192;       // nb floats

    hadar_prep<<<1, 256, 0, stream>>>(s_sky, s_ground, library, wg, cand);
    hadar_main<<<nb, BLK, 0, stream>>>(s_obs, library, cand, out, partials, N);

    const size_t NN = (size_t)N;
    float* obj_out = out + 4 * NN + 2 * (size_t)C_CH * NN;
    hadar_reduce<<<1, 256, 0, stream>>>(partials, nb, obj_out, 1.0f / (float)N);
}

// Round 7
// 766.870 us; speedup vs baseline: 1.1112x; 1.1112x over previous
//
#include <hip/hip_runtime.h>
#include <math.h>

#define C_CH 54
#define CP   64      // candidate row stride: [0..53]=cand, 54=candsq, 55=tcand, 56=libmean
#define NT   20
#define NM   6
#define NK   120     // NM * NT
#define BLK  256

typedef float sf16 __attribute__((ext_vector_type(16)));
typedef float sf8  __attribute__((ext_vector_type(8)));

// ---------------- prep: candidate table (CP=64 rows) into workspace ----------------
__global__ __launch_bounds__(256) void hadar_prep(
    const float* __restrict__ s_sky, const float* __restrict__ s_ground,
    const float* __restrict__ library, const float* __restrict__ wg,
    float* __restrict__ cand)
{
    __shared__ float xamb[C_CH];
    __shared__ float tc[NT];
    __shared__ float lm[NM];
    const int tid = threadIdx.x;
    if (tid < NT) tc[tid] = 250.0f + (float)tid * (100.0f / 19.0f);
    if (tid < C_CH) xamb[tid] = 0.5f * s_sky[tid] + 0.5f * s_ground[tid];
    if (tid < NM) {
        float s = 0.0f;
        for (int c = 0; c < C_CH; ++c) s += library[tid * C_CH + c];
        lm[tid] = s / (float)C_CH;
    }
    __syncthreads();

    const float c1 = 1.191042e-8f, c2 = 1.4387752f;
    for (int idx = tid; idx < NK * CP; idx += 256) {
        const int k = idx >> 6, c = idx & 63;
        float v = 0.0f;
        if (c < C_CH) {
            const int m = k / NT, t = k - m * NT;
            const float nu = wg[c];
            const float B = c1 * nu * nu * nu / expm1f(c2 * nu / tc[t]);
            const float e = library[m * C_CH + c];
            v = e * B + (1.0f - e) * xamb[c];
        }
        cand[idx] = v;
    }
    __syncthreads();

    if (tid < NK) {
        float s = 0.0f;
        for (int c = 0; c < C_CH; ++c) { float v = cand[tid * CP + c]; s += v * v; }
        const int m = tid / NT, t = tid - m * NT;
        cand[tid * CP + 54] = s;        // candsq
        cand[tid * CP + 55] = tc[t];    // best_t value for this k
        cand[tid * CP + 56] = lm[m];    // texture value for this k
    }
}

// element c of the current candidate row held in SGPRs (c is compile-time after unroll)
#define CE(c) ((c) < 16 ? q0[(c)] : (c) < 32 ? q1[(c)-16] : (c) < 48 ? q2[(c)-32] : q3[(c)-48])

// ---------------- main: one pixel per thread, candidate rows via scalar loads ----------
// Convoy-breaking: each wave starts its k-scan at a different rotation so the
// machine's waves stream DIFFERENT table lines concurrently (L2/SQC spread +
// wave destaggering for latency hiding). rot is wave-uniform; readfirstlane
// forces it into an SGPR so pk stays scalar (round-6 compile fix).
__global__ __launch_bounds__(BLK) void hadar_main(
    const float* __restrict__ s_obs,
    const float* __restrict__ library,
    const float* __restrict__ cand,
    float* __restrict__ out, float* __restrict__ partials, int N)
{
    const int tid = threadIdx.x;
    const long long n0 = (long long)blockIdx.x * BLK + tid;
    const bool v0 = (n0 < N);

    // pixel row in VGPRs (54 floats)
    float row0[C_CH];
    if (v0) {
        const float2* rp = (const float2*)(s_obs + n0 * C_CH);
        #pragma unroll
        for (int i = 0; i < C_CH / 2; ++i) {
            float2 w = rp[i];
            row0[2 * i] = w.x; row0[2 * i + 1] = w.y;
        }
    } else {
        #pragma unroll
        for (int c = 0; c < C_CH; ++c) row0[c] = 0.0f;
    }

    // ssq, same sequential order as before
    float ssq0 = 0.0f;
    #pragma unroll
    for (int c = 0; c < C_CH; ++c) ssq0 += row0[c] * row0[c];

    float bl0 = 3.4e38f;
    int bk0 = NK;   // sentinel larger than any real k

    // per-wave rotation: 15 distinct starts, step 8 (15*8 = 120).
    // readfirstlane makes the wave-uniform value SGPR-resident.
    const int wid = __builtin_amdgcn_readfirstlane(tid >> 6);
    const int rot = (int)((blockIdx.x * 4u + (unsigned)wid) % 15u) * 8;

    int kk = rot;
    const float* pk = cand + (size_t)rot * CP;
    #pragma unroll 1
    for (int i = 0; i < NK; ++i) {
        sf16 q0, q1, q2;
        sf8  q3;
        asm volatile("s_load_dwordx16 %0, %1, 0x0"  : "=s"(q0) : "s"(pk));
        asm volatile("s_load_dwordx16 %0, %1, 0x40" : "=s"(q1) : "s"(pk));
        asm volatile("s_load_dwordx16 %0, %1, 0x80" : "=s"(q2) : "s"(pk));
        asm volatile("s_load_dwordx8  %0, %1, 0xc0" : "=s"(q3) : "s"(pk));
        // tie the wait to the loaded values so consumers can't be hoisted above it
        asm volatile("s_waitcnt lgkmcnt(0)" : "+s"(q0), "+s"(q1), "+s"(q2), "+s"(q3));

        float a0[4] = {0.f, 0.f, 0.f, 0.f};
        #pragma unroll
        for (int c = 0; c < C_CH; ++c) {
            a0[c & 3] += row0[c] * CE(c);
        }
        const float sq = q3[6];   // slot 54 = candsq
        const float d0 = (a0[0] + a0[1]) + (a0[2] + a0[3]);
        const float l0 = (ssq0 - 2.0f * d0) + sq;
        // lexicographic (loss, k) min == first-min in k order
        if (l0 < bl0 || (l0 == bl0 && kk < bk0)) { bl0 = l0; bk0 = kk; }

        ++kk; pk += CP;
        if (kk == NK) { kk = 0; pk = cand; }
    }

    // ---- outputs ----
    const size_t NN = (size_t)N;
    const size_t NC = (size_t)C_CH * NN;
    float lsum = 0.0f;

    if (v0) {
        lsum = bl0;
        const int m = bk0 / NT;
        const float* crow = cand + (size_t)bk0 * CP;

        out[n0] = crow[55];                      // best_t
        out[NN + NC + n0] = 0.5f;                // best_v
        out[2 * NN + NC + n0] = 0.0f;            // beta
        out[3 * NN + NC + n0] = crow[56];        // texture

        // best_e = library[m]
        float2* bep = (float2*)(out + NN + (size_t)n0 * C_CH);
        const float2* lp = (const float2*)(library + m * C_CH);
        #pragma unroll
        for (int i = 0; i < C_CH / 2; ++i) bep[i] = lp[i];

        // s_recon = cand[bk0]
        float2* srp = (float2*)(out + 4 * NN + NC + (size_t)n0 * C_CH);
        const float2* cp2 = (const float2*)crow;
        #pragma unroll
        for (int i = 0; i < C_CH / 2; ++i) srp[i] = cp2[i];
    }

    // ---- deterministic block reduction of best_loss sum ----
    __shared__ float red[BLK];
    red[tid] = lsum;
    __syncthreads();
    #pragma unroll
    for (int s = BLK / 2; s > 0; s >>= 1) {
        if (tid < s) red[tid] += red[tid + s];
        __syncthreads();
    }
    if (tid == 0) partials[blockIdx.x] = red[0];
}

// ---------------- final reduce: objective = mean(best_loss) ----------------
__global__ __launch_bounds__(256) void hadar_reduce(
    const float* __restrict__ partials, int nb, float* __restrict__ obj_out, float invN)
{
    __shared__ float red[256];
    float s = 0.0f;
    for (int i = threadIdx.x; i < nb; i += 256) s += partials[i];
    red[threadIdx.x] = s;
    __syncthreads();
    #pragma unroll
    for (int st = 128; st > 0; st >>= 1) {
        if (threadIdx.x < st) red[threadIdx.x] += red[threadIdx.x + st];
        __syncthreads();
    }
    if (threadIdx.x == 0) *obj_out = red[0] * invN;
}

extern "C" void kernel_launch(void* const* d_in, const int* in_sizes, int n_in,
                              void* d_out, int out_size, void* d_ws, size_t ws_size,
                              hipStream_t stream)
{
    const float* s_obs    = (const float*)d_in[0];
    const float* s_sky    = (const float*)d_in[1];
    const float* s_ground = (const float*)d_in[2];
    const float* library  = (const float*)d_in[3];
    const float* wg       = (const float*)d_in[4];
    float* out = (float*)d_out;

    const int N  = in_sizes[0] / C_CH;
    const int nb = (N + BLK - 1) / BLK;

    float* ws       = (float*)d_ws;
    float* cand     = ws;              // NK*CP = 7680 floats
    float* partials = ws + 8192;       // nb floats

    hadar_prep<<<1, 256, 0, stream>>>(s_sky, s_ground, library, wg, cand);
    hadar_main<<<nb, BLK, 0, stream>>>(s_obs, library, cand, out, partials, N);

    const size_t NN = (size_t)N;
    float* obj_out = out + 4 * NN + 2 * (size_t)C_CH * NN;
    hadar_reduce<<<1, 256, 0, stream>>>(partials, nb, obj_out, 1.0f / (float)N);
}